// Round 5
// baseline (1173.592 us; speedup 1.0000x reference)
//
#include <hip/hip_runtime.h>
#include <math.h>

typedef unsigned short ushort_t;
typedef __attribute__((ext_vector_type(8))) short short8;
typedef __attribute__((ext_vector_type(4))) float floatx4;

#define BATCH 4
#define SEQ   2048
#define EMB   1024

// ---------------------------------------------------------------------------
// bf16 helpers (RNE)
// ---------------------------------------------------------------------------
__device__ __forceinline__ ushort_t f2bf(float f) {
    unsigned u = __float_as_uint(f);
    u += 0x7fff + ((u >> 16) & 1);
    return (ushort_t)(u >> 16);
}
__device__ __forceinline__ float bf2f(ushort_t h) {
    return __uint_as_float(((unsigned)h) << 16);
}

// ---------------------------------------------------------------------------
// Elementwise split: fp32 -> (hi, lo) bf16 arrays. n4 = count/4.
// ---------------------------------------------------------------------------
__global__ __launch_bounds__(256)
void split_elem(const float* __restrict__ in, ushort_t* __restrict__ hi,
                ushort_t* __restrict__ lo, size_t n4)
{
    size_t i = (size_t)blockIdx.x * 256 + threadIdx.x;
    if (i >= n4) return;
    float4 v = reinterpret_cast<const float4*>(in)[i];
    float vv[4] = {v.x, v.y, v.z, v.w};
    unsigned h[4], l[4];
    #pragma unroll
    for (int j = 0; j < 4; ++j) {
        h[j] = f2bf(vv[j]);
        l[j] = f2bf(vv[j] - bf2f((ushort_t)h[j]));
    }
    uint2 hv, lv;
    hv.x = h[0] | (h[1] << 16); hv.y = h[2] | (h[3] << 16);
    lv.x = l[0] | (l[1] << 16); lv.y = l[2] | (l[3] << 16);
    *reinterpret_cast<uint2*>(hi + i * 4) = hv;
    *reinterpret_cast<uint2*>(lo + i * 4) = lv;
}

// ---------------------------------------------------------------------------
// Split + transpose: W [rows][cols] fp32 -> T [cols][rows] bf16 hi/lo.
// ---------------------------------------------------------------------------
__global__ __launch_bounds__(256)
void split_transpose(const float* __restrict__ W, ushort_t* __restrict__ Thi,
                     ushort_t* __restrict__ Tlo, int rows, int cols)
{
    __shared__ float tile[32][33];
    const int r0 = blockIdx.y * 32, c0 = blockIdx.x * 32;
    const int tr = threadIdx.x >> 5;   // 0..7
    const int tc = threadIdx.x & 31;
    #pragma unroll
    for (int rr = 0; rr < 32; rr += 8)
        tile[tr + rr][tc] = W[(size_t)(r0 + tr + rr) * cols + c0 + tc];
    __syncthreads();
    #pragma unroll
    for (int rr = 0; rr < 32; rr += 8) {
        float v = tile[tc][tr + rr];
        size_t o = (size_t)(c0 + tr + rr) * rows + r0 + tc;
        ushort_t h = f2bf(v);
        Thi[o] = h;
        Tlo[o] = f2bf(v - bf2f(h));
    }
}

// ---------------------------------------------------------------------------
// NT MFMA GEMM, 16x16x32 bf16, LDS-staged vectorized epilogue:
//   C[m][n] = alpha * sum_k A[m][k]*B[n][k]  (+ bias)
// TERMS  : 3 -> fp32 emulation (hh + hl + lh), split hi/lo planes, BKT=32
//          1 -> plain bf16 (hi plane only), BKT=64
// BIAS_MODE : 0 none, 1 per-n (bias[col]), 2 per-m (bias[row])
// STORE_MODE: 0 fp32 -> C ; 1 split bf16 -> Chi/Clo ; 2 bf16 -> Chi
// Batched via blockIdx.z with element strides bsA/bsB/bsC.
// ---------------------------------------------------------------------------
template<int TERMS, int BIAS_MODE, int STORE_MODE>
__global__ __launch_bounds__(256)
void gemm16(const ushort_t* __restrict__ Ahi, const ushort_t* __restrict__ Alo,
            int ldA, size_t bsA,
            const ushort_t* __restrict__ Bhi, const ushort_t* __restrict__ Blo,
            int ldB, size_t bsB,
            float* __restrict__ C, ushort_t* __restrict__ Chi, ushort_t* __restrict__ Clo,
            int ldC, size_t bsC,
            int K, float alpha, const float* __restrict__ bias)
{
    constexpr int PL  = (TERMS == 3) ? 2 : 1;      // LDS planes
    constexpr int BKT = (TERMS == 3) ? 32 : 64;    // K-tile
    constexpr int LK  = BKT + 8;                   // padded LDS k-stride (bf16)
    constexpr int KV  = BKT / 8;                   // int4 chunks per row
    constexpr int RP  = 256 / KV;                  // rows staged per pass
    constexpr int NP  = 128 / RP;                  // passes
    constexpr int KS  = BKT / 32;                  // MFMA k-steps per tile

    // Shared memory: staging buffers during K-loop, per-wave fp32 transpose
    // buffer (4 waves x 32 rows x 68 floats, 16B-aligned rows) in the epilogue.
    constexpr int STAGE_BYTES = 2 * PL * 128 * LK * 2;
    constexpr int EPIL_BYTES  = 4 * 32 * 68 * 4;
    constexpr int SMEM_BYTES  = STAGE_BYTES > EPIL_BYTES ? STAGE_BYTES : EPIL_BYTES;
    __shared__ alignas(16) char smem[SMEM_BYTES];
    auto As = reinterpret_cast<ushort_t (*)[128][LK]>(smem);
    auto Bs = reinterpret_cast<ushort_t (*)[128][LK]>(smem + PL * 128 * LK * 2);

    const size_t zA = (size_t)blockIdx.z * bsA;
    const size_t zB = (size_t)blockIdx.z * bsB;
    const size_t zC = (size_t)blockIdx.z * bsC;

    const int t  = threadIdx.x;
    const int m0 = blockIdx.y * 128;
    const int n0 = blockIdx.x * 128;

    const int sr = t / KV;          // staging row within pass
    const int sk = (t % KV) * 8;    // staging k-offset (elems)

    const int lane = t & 63;
    const int wid  = t >> 6;        // wave 0..3
    const int wm = (wid & 1) * 64;
    const int wn = (wid >> 1) * 64;
    const int fr = lane & 15;       // fragment row (m or n)
    const int fq = lane >> 4;       // k-quad: frag k = fq*8 + j

    floatx4 acc[4][4];
    #pragma unroll
    for (int i = 0; i < 4; ++i)
        #pragma unroll
        for (int j = 0; j < 4; ++j)
            #pragma unroll
            for (int r = 0; r < 4; ++r) acc[i][j][r] = 0.f;

    for (int k0 = 0; k0 < K; k0 += BKT) {
        int4 argh[NP], brgh[NP], argl[NP], brgl[NP];
        #pragma unroll
        for (int p = 0; p < NP; ++p) {
            const int row = p * RP + sr;
            const size_t ao = zA + (size_t)(m0 + row) * ldA + k0 + sk;
            const size_t bo = zB + (size_t)(n0 + row) * ldB + k0 + sk;
            argh[p] = *reinterpret_cast<const int4*>(Ahi + ao);
            brgh[p] = *reinterpret_cast<const int4*>(Bhi + bo);
            if constexpr (TERMS == 3) {
                argl[p] = *reinterpret_cast<const int4*>(Alo + ao);
                brgl[p] = *reinterpret_cast<const int4*>(Blo + bo);
            }
        }

        __syncthreads();   // prior iter's LDS reads complete
        #pragma unroll
        for (int p = 0; p < NP; ++p) {
            const int row = p * RP + sr;
            *reinterpret_cast<int4*>(&As[0][row][sk]) = argh[p];
            *reinterpret_cast<int4*>(&Bs[0][row][sk]) = brgh[p];
            if constexpr (TERMS == 3) {
                *reinterpret_cast<int4*>(&As[1][row][sk]) = argl[p];
                *reinterpret_cast<int4*>(&Bs[1][row][sk]) = brgl[p];
            }
        }
        __syncthreads();

        #pragma unroll
        for (int ks = 0; ks < KS; ++ks) {
            const int ko = ks * 32 + fq * 8;
            short8 ah[4], al[4];
            #pragma unroll
            for (int i = 0; i < 4; ++i) {
                ah[i] = *reinterpret_cast<const short8*>(&As[0][wm + i*16 + fr][ko]);
                if constexpr (TERMS == 3)
                    al[i] = *reinterpret_cast<const short8*>(&As[1][wm + i*16 + fr][ko]);
            }
            #pragma unroll
            for (int j = 0; j < 4; ++j) {
                short8 bh = *reinterpret_cast<const short8*>(&Bs[0][wn + j*16 + fr][ko]);
                short8 bl;
                if constexpr (TERMS == 3)
                    bl = *reinterpret_cast<const short8*>(&Bs[1][wn + j*16 + fr][ko]);
                #pragma unroll
                for (int i = 0; i < 4; ++i) {
                    acc[i][j] = __builtin_amdgcn_mfma_f32_16x16x32_bf16(ah[i], bh, acc[i][j], 0, 0, 0);
                    if constexpr (TERMS == 3) {
                        acc[i][j] = __builtin_amdgcn_mfma_f32_16x16x32_bf16(ah[i], bl, acc[i][j], 0, 0, 0);
                        acc[i][j] = __builtin_amdgcn_mfma_f32_16x16x32_bf16(al[i], bh, acc[i][j], 0, 0, 0);
                    }
                }
            }
        }
    }

    // -----------------------------------------------------------------------
    // Epilogue: per-wave LDS transpose -> wide coalesced stores.
    // Acc layout (16x16 C/D, m89): row = wm + i*16 + fq*4 + r, col = wn + j*16 + fr.
    // Each wave owns quadrant [wm..wm+63] x [wn..wn+63]; processed in two
    // 32-row phases through a 32x68-float per-wave LDS buffer.
    // -----------------------------------------------------------------------
    __syncthreads();   // all waves done reading As/Bs before we overwrite
    float* ebuf = reinterpret_cast<float*>(smem) + wid * (32 * 68);

    #pragma unroll
    for (int p = 0; p < 2; ++p) {
        #pragma unroll
        for (int ii = 0; ii < 2; ++ii) {
            const int i = 2 * p + ii;
            #pragma unroll
            for (int j = 0; j < 4; ++j) {
                const int col = n0 + wn + j*16 + fr;
                float bn = 0.f;
                if (BIAS_MODE == 1) bn = bias[col];
                #pragma unroll
                for (int r = 0; r < 4; ++r) {
                    const int row = m0 + wm + i*16 + fq*4 + r;
                    float v = acc[i][j][r] * alpha + bn;
                    if (BIAS_MODE == 2) v += bias[row];
                    ebuf[(ii*16 + fq*4 + r) * 68 + j*16 + fr] = v;
                }
            }
        }
        __syncthreads();   // also orders this wave's LDS writes vs reads

        #pragma unroll
        for (int it = 0; it < 8; ++it) {
            const int lr = fq + 4 * it;              // 0..31
            float4 v4 = *reinterpret_cast<float4*>(&ebuf[lr * 68 + fr * 4]);
            const int grow = m0 + wm + p*32 + lr;
            const int gcol = n0 + wn + fr*4;
            const size_t o = zC + (size_t)grow * ldC + gcol;
            if constexpr (STORE_MODE == 0) {
                *reinterpret_cast<float4*>(C + o) = v4;
            } else if constexpr (STORE_MODE == 1) {
                unsigned h0 = f2bf(v4.x), h1 = f2bf(v4.y), h2 = f2bf(v4.z), h3 = f2bf(v4.w);
                unsigned l0 = f2bf(v4.x - bf2f((ushort_t)h0));
                unsigned l1 = f2bf(v4.y - bf2f((ushort_t)h1));
                unsigned l2 = f2bf(v4.z - bf2f((ushort_t)h2));
                unsigned l3 = f2bf(v4.w - bf2f((ushort_t)h3));
                uint2 hv, lv;
                hv.x = h0 | (h1 << 16); hv.y = h2 | (h3 << 16);
                lv.x = l0 | (l1 << 16); lv.y = l2 | (l3 << 16);
                *reinterpret_cast<uint2*>(Chi + o) = hv;
                *reinterpret_cast<uint2*>(Clo + o) = lv;
            } else {
                unsigned h0 = f2bf(v4.x), h1 = f2bf(v4.y), h2 = f2bf(v4.z), h3 = f2bf(v4.w);
                uint2 hv;
                hv.x = h0 | (h1 << 16); hv.y = h2 | (h3 << 16);
                *reinterpret_cast<uint2*>(Chi + o) = hv;
            }
        }
        if (p == 0) __syncthreads();   // buffer reuse across phases
    }
}

// ---------------------------------------------------------------------------
// Column-softmax (softmax over the QUERY axis => per-column over rows).
// ---------------------------------------------------------------------------
__global__ __launch_bounds__(256)
void colstats_partial(const float* __restrict__ S, float* __restrict__ mP,
                      float* __restrict__ ZP, int rows_total, int cols, int rows_per)
{
    const int b = blockIdx.z;
    const int c = blockIdx.x * 256 + threadIdx.x;
    const int r0 = blockIdx.y * rows_per;
    const float* Sp = S + ((size_t)b * rows_total + r0) * cols + c;

    float m = -INFINITY, Z = 0.f;
    for (int q = 0; q < rows_per; ++q) {
        float s = Sp[(size_t)q * cols];
        float nm = fmaxf(m, s);
        Z = Z * __expf(m - nm) + __expf(s - nm);
        m = nm;
    }
    size_t o = ((size_t)b * gridDim.y + blockIdx.y) * cols + c;
    mP[o] = m;
    ZP[o] = Z;
}

__global__ __launch_bounds__(256)
void colstats_combine(const float* __restrict__ mP, const float* __restrict__ ZP,
                      float* __restrict__ mOut, float* __restrict__ rZ,
                      int cols, int chunks)
{
    const int b = blockIdx.y;
    const int c = blockIdx.x * 256 + threadIdx.x;
    float m = -INFINITY, Z = 0.f;
    for (int ch = 0; ch < chunks; ++ch) {
        size_t o = ((size_t)b * chunks + ch) * cols + c;
        float mi = mP[o], Zi = ZP[o];
        float nm = fmaxf(m, mi);
        Z = Z * __expf(m - nm) + Zi * __expf(mi - nm);
        m = nm;
    }
    mOut[(size_t)b * cols + c] = m;
    rZ[(size_t)b * cols + c]   = 1.0f / Z;
}

// ---------------------------------------------------------------------------
// Normalize: P = exp(S - m_col) * rZ_col -> plain bf16.
// ---------------------------------------------------------------------------
__global__ __launch_bounds__(256)
void normalize_bf16(const float* __restrict__ S, const float* __restrict__ mIn,
                    const float* __restrict__ rZ, ushort_t* __restrict__ Phi,
                    size_t total4, int cols, int rowscols)
{
    size_t i4 = (size_t)blockIdx.x * 256 + threadIdx.x;
    if (i4 >= total4) return;
    size_t base = i4 * 4;
    int b   = (int)(base / (size_t)rowscols);
    int col = (int)(base % (size_t)cols);
    float4 s = *reinterpret_cast<const float4*>(S + base);
    const float* mv = mIn + (size_t)b * cols + col;
    const float* zv = rZ  + (size_t)b * cols + col;
    unsigned h0 = f2bf(__expf(s.x - mv[0]) * zv[0]);
    unsigned h1 = f2bf(__expf(s.y - mv[1]) * zv[1]);
    unsigned h2 = f2bf(__expf(s.z - mv[2]) * zv[2]);
    unsigned h3 = f2bf(__expf(s.w - mv[3]) * zv[3]);
    uint2 hv;
    hv.x = h0 | (h1 << 16);
    hv.y = h2 | (h3 << 16);
    *reinterpret_cast<uint2*>(Phi + base) = hv;
}

// ---------------------------------------------------------------------------
extern "C" void kernel_launch(void* const* d_in, const int* in_sizes, int n_in,
                              void* d_out, int out_size, void* d_ws, size_t ws_size,
                              hipStream_t stream)
{
    const float* x  = (const float*)d_in[0];
    const float* Wq = (const float*)d_in[1];
    const float* bq = (const float*)d_in[2];
    const float* Wk = (const float*)d_in[3];
    const float* bk = (const float*)d_in[4];
    const float* Wv = (const float*)d_in[5];
    const float* bv = (const float*)d_in[6];

    const int S = SEQ, E = EMB;
    const size_t MT = (size_t)BATCH * S;      // 8192
    const size_t MB = 1024 * 1024;

    // Workspace layout (stream-ordered overlays; lifetimes disjoint):
    //   [0,64)    Sc fp32                     (live: scores..normalize)
    //   [0,16)    xhi | [16,32) xlo           (live: split..projections)
    //   [32,44)   Wt hi/lo x3                 (live: transpose..projections)
    //   [64,96)   Qhi/Qlo -> later Phi        (Q dead after scores)
    //   [96,128)  Khi/Klo
    //   [128,144) Vthi (bf16 only)
    //   [160,..)  softmax stats
    char* base = (char*)d_ws;
    float*    Sc   = (float*)base;
    ushort_t* xhi  = (ushort_t*)base;
    ushort_t* xlo  = (ushort_t*)(base + 16 * MB);
    ushort_t* Wqth = (ushort_t*)(base + 32 * MB);
    ushort_t* Wqtl = (ushort_t*)(base + 34 * MB);
    ushort_t* Wkth = (ushort_t*)(base + 36 * MB);
    ushort_t* Wktl = (ushort_t*)(base + 38 * MB);
    ushort_t* Wvth = (ushort_t*)(base + 40 * MB);
    ushort_t* Wvtl = (ushort_t*)(base + 42 * MB);
    ushort_t* Qhi  = (ushort_t*)(base + 64 * MB);
    ushort_t* Qlo  = (ushort_t*)(base + 80 * MB);
    ushort_t* Khi  = (ushort_t*)(base + 96 * MB);
    ushort_t* Klo  = (ushort_t*)(base + 112 * MB);
    ushort_t* Phi  = (ushort_t*)(base + 64 * MB);   // overlays Q (dead)
    ushort_t* Vth  = (ushort_t*)(base + 128 * MB);
    float* mC = (float*)(base + 160 * MB);
    float* rZ = mC + (size_t)BATCH * S;
    float* mP = rZ + (size_t)BATCH * S;
    float* ZP = mP + (size_t)BATCH * 8 * S;

    dim3 blk(256);

    // 1) Split x into bf16 hi/lo
    split_elem<<<8192, blk, 0, stream>>>(x, xhi, xlo, MT * E / 4);

    // 2) Split+transpose weights: Wt [n][e]
    dim3 gt(E / 32, E / 32);
    split_transpose<<<gt, blk, 0, stream>>>(Wq, Wqth, Wqtl, E, E);
    split_transpose<<<gt, blk, 0, stream>>>(Wk, Wkth, Wktl, E, E);
    split_transpose<<<gt, blk, 0, stream>>>(Wv, Wvth, Wvtl, E, E);

    // 3) Projections (NT, 3-term): Q/K = x . Wt^T + b, split-stored
    dim3 gq(E / 128, MT / 128, 1);   // (8, 64)
    gemm16<3, 1, 1><<<gq, blk, 0, stream>>>(xhi, xlo, E, 0, Wqth, Wqtl, E, 0,
        nullptr, Qhi, Qlo, E, 0, E, 1.f, bq);
    gemm16<3, 1, 1><<<gq, blk, 0, stream>>>(xhi, xlo, E, 0, Wkth, Wktl, E, 0,
        nullptr, Khi, Klo, E, 0, E, 1.f, bk);
    // Vt[d][key] = Wvt . x^T + bv (per-row bias), bf16-only store, ldC = MT
    dim3 gv(MT / 128, E / 128, 1);   // (64, 8)
    gemm16<3, 2, 2><<<gv, blk, 0, stream>>>(Wvth, Wvtl, E, 0, xhi, xlo, E, 0,
        nullptr, Vth, nullptr, (int)MT, 0, E, 1.f, bv);

    // 4) Scores (NT, 3-term, batched): Sc_b = Q_b . K_b^T / 32, fp32
    dim3 gs(S / 128, S / 128, BATCH);   // (16,16,4)
    gemm16<3, 0, 0><<<gs, blk, 0, stream>>>(Qhi, Qlo, E, (size_t)S * E,
        Khi, Klo, E, (size_t)S * E,
        Sc, nullptr, nullptr, S, (size_t)S * S, E, 0.03125f, nullptr);

    // 5) Column softmax stats
    dim3 g3(S / 256, 8, BATCH);
    colstats_partial<<<g3, blk, 0, stream>>>(Sc, mP, ZP, S, S, S / 8);
    dim3 g4(S / 256, BATCH);
    colstats_combine<<<g4, blk, 0, stream>>>(mP, ZP, mC, rZ, S, 8);

    // 6) Normalize -> plain bf16 P
    size_t total4 = (size_t)BATCH * S * S / 4;
    normalize_bf16<<<(unsigned)((total4 + 255) / 256), blk, 0, stream>>>(
        Sc, mC, rZ, Phi, total4, S, S * S);

    // 7) Output (NT, 1-term bf16, batched): out_b = P_b . Vt^T
    dim3 go(E / 128, S / 128, BATCH);   // (8,16,4)
    gemm16<1, 0, 0><<<go, blk, 0, stream>>>(Phi, nullptr, S, (size_t)S * S,
        Vth, nullptr, (int)MT, (size_t)S,
        (float*)d_out, nullptr, nullptr, E, (size_t)S * E, S, 1.f, nullptr);
}

// Round 6
// 649.027 us; speedup vs baseline: 1.8082x; 1.8082x over previous
//
#include <hip/hip_runtime.h>
#include <math.h>

typedef unsigned short ushort_t;
typedef __attribute__((ext_vector_type(8))) short short8;
typedef __attribute__((ext_vector_type(4))) float floatx4;

#define BATCH 4
#define SEQ   2048
#define EMB   1024

// MFMA GEMM tile
#define GBM 128
#define GBN 128
#define GBK 32
#define LDSK 40   // padded LDS k-stride in bf16 elems (80 B rows -> 2-way bank alias, free)

// ---------------------------------------------------------------------------
// bf16 split helpers (RNE)
// ---------------------------------------------------------------------------
__device__ __forceinline__ ushort_t f2bf(float f) {
    unsigned u = __float_as_uint(f);
    u += 0x7fff + ((u >> 16) & 1);
    return (ushort_t)(u >> 16);
}
__device__ __forceinline__ float bf2f(ushort_t h) {
    return __uint_as_float(((unsigned)h) << 16);
}

// ---------------------------------------------------------------------------
// Elementwise split: fp32 -> (hi, lo) bf16 arrays. n4 = count/4.
// ---------------------------------------------------------------------------
__global__ __launch_bounds__(256)
void split_elem(const float* __restrict__ in, ushort_t* __restrict__ hi,
                ushort_t* __restrict__ lo, size_t n4)
{
    size_t i = (size_t)blockIdx.x * 256 + threadIdx.x;
    if (i >= n4) return;
    float4 v = reinterpret_cast<const float4*>(in)[i];
    float vv[4] = {v.x, v.y, v.z, v.w};
    unsigned h[4], l[4];
    #pragma unroll
    for (int j = 0; j < 4; ++j) {
        h[j] = f2bf(vv[j]);
        l[j] = f2bf(vv[j] - bf2f((ushort_t)h[j]));
    }
    uint2 hv, lv;
    hv.x = h[0] | (h[1] << 16); hv.y = h[2] | (h[3] << 16);
    lv.x = l[0] | (l[1] << 16); lv.y = l[2] | (l[3] << 16);
    *reinterpret_cast<uint2*>(hi + i * 4) = hv;
    *reinterpret_cast<uint2*>(lo + i * 4) = lv;
}

// ---------------------------------------------------------------------------
// Split + transpose: W [rows][cols] fp32 -> T [cols][rows] bf16 hi/lo.
// ---------------------------------------------------------------------------
__global__ __launch_bounds__(256)
void split_transpose(const float* __restrict__ W, ushort_t* __restrict__ Thi,
                     ushort_t* __restrict__ Tlo, int rows, int cols)
{
    __shared__ float tile[32][33];
    const int r0 = blockIdx.y * 32, c0 = blockIdx.x * 32;
    const int tr = threadIdx.x >> 5;   // 0..7
    const int tc = threadIdx.x & 31;
    #pragma unroll
    for (int rr = 0; rr < 32; rr += 8)
        tile[tr + rr][tc] = W[(size_t)(r0 + tr + rr) * cols + c0 + tc];
    __syncthreads();
    #pragma unroll
    for (int rr = 0; rr < 32; rr += 8) {
        float v = tile[tc][tr + rr];
        size_t o = (size_t)(c0 + tr + rr) * rows + r0 + tc;
        ushort_t h = f2bf(v);
        Thi[o] = h;
        Tlo[o] = f2bf(v - bf2f(h));
    }
}

// ---------------------------------------------------------------------------
// NT MFMA GEMM on split-bf16 pairs (VERBATIM round-2 kernel):
//   C[m][n] = alpha * sum_k A[m][k]*B[n][k]  (+ bias)
// A = Ahi+Alo, B = Bhi+Blo (fp32 emulation: hh + hl + lh).
// BIAS_MODE: 0 none, 1 per-n (bias[col]), 2 per-m (bias[row])
// STORE_SPLIT: 0 -> fp32 to C; 1 -> split bf16 to Chi/Clo
// Batched via blockIdx.z with element strides bsA/bsB/bsC.
// ---------------------------------------------------------------------------
template<int BIAS_MODE, int STORE_SPLIT>
__global__ __launch_bounds__(256)
void gemm_bf16pair(const ushort_t* __restrict__ Ahi, const ushort_t* __restrict__ Alo,
                   int ldA, size_t bsA,
                   const ushort_t* __restrict__ Bhi, const ushort_t* __restrict__ Blo,
                   int ldB, size_t bsB,
                   float* __restrict__ C, ushort_t* __restrict__ Chi, ushort_t* __restrict__ Clo,
                   int ldC, size_t bsC,
                   int K, float alpha, const float* __restrict__ bias)
{
    const size_t zA = (size_t)blockIdx.z * bsA;
    const size_t zB = (size_t)blockIdx.z * bsB;
    const size_t zC = (size_t)blockIdx.z * bsC;

    __shared__ alignas(16) ushort_t As[2][GBM][LDSK];   // [hi/lo][m][k]
    __shared__ alignas(16) ushort_t Bs[2][GBN][LDSK];   // [hi/lo][n][k]

    const int t  = threadIdx.x;
    const int m0 = blockIdx.y * GBM;
    const int n0 = blockIdx.x * GBN;

    // staging: chunk c covers (row=c>>2, k=(c&3)*8 .. +7); thread owns c=t and c=t+256
    const int sr = t >> 2;          // 0..63
    const int sk = (t & 3) * 8;

    const int lane = t & 63;
    const int wid  = t >> 6;        // wave 0..3
    const int wm = (wid & 1) * 64;
    const int wn = (wid >> 1) * 64;
    const int fr = lane & 15;       // fragment row (m or n)
    const int fq = lane >> 4;       // k-quad: k = fq*8 + j

    floatx4 acc[4][4];
    #pragma unroll
    for (int i = 0; i < 4; ++i)
        #pragma unroll
        for (int j = 0; j < 4; ++j)
            #pragma unroll
            for (int r = 0; r < 4; ++r) acc[i][j][r] = 0.f;

    for (int k0 = 0; k0 < K; k0 += GBK) {
        const size_t aoff = zA + (size_t)(m0 + sr) * ldA + k0 + sk;
        const size_t boff = zB + (size_t)(n0 + sr) * ldB + k0 + sk;
        const size_t astep = (size_t)64 * ldA;
        const size_t bstep = (size_t)64 * ldB;
        int4 a0 = *reinterpret_cast<const int4*>(Ahi + aoff);
        int4 a1 = *reinterpret_cast<const int4*>(Ahi + aoff + astep);
        int4 a2 = *reinterpret_cast<const int4*>(Alo + aoff);
        int4 a3 = *reinterpret_cast<const int4*>(Alo + aoff + astep);
        int4 b0 = *reinterpret_cast<const int4*>(Bhi + boff);
        int4 b1 = *reinterpret_cast<const int4*>(Bhi + boff + bstep);
        int4 b2 = *reinterpret_cast<const int4*>(Blo + boff);
        int4 b3 = *reinterpret_cast<const int4*>(Blo + boff + bstep);

        __syncthreads();   // prior iter's LDS reads complete
        *reinterpret_cast<int4*>(&As[0][sr     ][sk]) = a0;
        *reinterpret_cast<int4*>(&As[0][sr + 64][sk]) = a1;
        *reinterpret_cast<int4*>(&As[1][sr     ][sk]) = a2;
        *reinterpret_cast<int4*>(&As[1][sr + 64][sk]) = a3;
        *reinterpret_cast<int4*>(&Bs[0][sr     ][sk]) = b0;
        *reinterpret_cast<int4*>(&Bs[0][sr + 64][sk]) = b1;
        *reinterpret_cast<int4*>(&Bs[1][sr     ][sk]) = b2;
        *reinterpret_cast<int4*>(&Bs[1][sr + 64][sk]) = b3;
        __syncthreads();

        short8 ah[4], al[4];
        #pragma unroll
        for (int i = 0; i < 4; ++i) {
            ah[i] = *reinterpret_cast<const short8*>(&As[0][wm + i*16 + fr][fq*8]);
            al[i] = *reinterpret_cast<const short8*>(&As[1][wm + i*16 + fr][fq*8]);
        }
        #pragma unroll
        for (int j = 0; j < 4; ++j) {
            short8 bh = *reinterpret_cast<const short8*>(&Bs[0][wn + j*16 + fr][fq*8]);
            short8 bl = *reinterpret_cast<const short8*>(&Bs[1][wn + j*16 + fr][fq*8]);
            #pragma unroll
            for (int i = 0; i < 4; ++i) {
                acc[i][j] = __builtin_amdgcn_mfma_f32_16x16x32_bf16(ah[i], bh, acc[i][j], 0, 0, 0);
                acc[i][j] = __builtin_amdgcn_mfma_f32_16x16x32_bf16(ah[i], bl, acc[i][j], 0, 0, 0);
                acc[i][j] = __builtin_amdgcn_mfma_f32_16x16x32_bf16(al[i], bh, acc[i][j], 0, 0, 0);
            }
        }
    }

    // Epilogue. C/D layout: col = lane&15, row = (lane>>4)*4 + r  [m89-verified]
    #pragma unroll
    for (int i = 0; i < 4; ++i) {
        #pragma unroll
        for (int j = 0; j < 4; ++j) {
            const int col = n0 + wn + j*16 + fr;
            float bn = 0.f;
            if (BIAS_MODE == 1) bn = bias[col];
            #pragma unroll
            for (int r = 0; r < 4; ++r) {
                const int row = m0 + wm + i*16 + fq*4 + r;
                float v = acc[i][j][r] * alpha + bn;
                if (BIAS_MODE == 2) v += bias[row];
                const size_t o = zC + (size_t)row * ldC + col;
                if (STORE_SPLIT) {
                    ushort_t h = f2bf(v);
                    Chi[o] = h;
                    Clo[o] = f2bf(v - bf2f(h));
                } else {
                    C[o] = v;
                }
            }
        }
    }
}

// ---------------------------------------------------------------------------
// NEW (only change vs round 2): plain 1-term bf16 NT GEMM for P @ V^T.
// BKT=64, LDS row stride 72 (144 B: 2-way bank alias, free). Same wave
// layout / epilogue as gemm_bf16pair, fp32 store, no bias.
// ---------------------------------------------------------------------------
__global__ __launch_bounds__(256)
void gemm_pv(const ushort_t* __restrict__ A, int ldA, size_t bsA,
             const ushort_t* __restrict__ B, int ldB, size_t bsB,
             float* __restrict__ C, int ldC, size_t bsC, int K)
{
    const size_t zA = (size_t)blockIdx.z * bsA;
    const size_t zB = (size_t)blockIdx.z * bsB;
    const size_t zC = (size_t)blockIdx.z * bsC;

    __shared__ alignas(16) ushort_t As[128][72];
    __shared__ alignas(16) ushort_t Bs[128][72];

    const int t  = threadIdx.x;
    const int m0 = blockIdx.y * 128;
    const int n0 = blockIdx.x * 128;

    const int sr = t >> 3;          // 0..31
    const int sk = (t & 7) * 8;     // 0..56

    const int lane = t & 63;
    const int wid  = t >> 6;
    const int wm = (wid & 1) * 64;
    const int wn = (wid >> 1) * 64;
    const int fr = lane & 15;
    const int fq = lane >> 4;

    floatx4 acc[4][4];
    #pragma unroll
    for (int i = 0; i < 4; ++i)
        #pragma unroll
        for (int j = 0; j < 4; ++j)
            #pragma unroll
            for (int r = 0; r < 4; ++r) acc[i][j][r] = 0.f;

    for (int k0 = 0; k0 < K; k0 += 64) {
        int4 av[4], bv[4];
        #pragma unroll
        for (int p = 0; p < 4; ++p) {
            const int row = p * 32 + sr;
            av[p] = *reinterpret_cast<const int4*>(A + zA + (size_t)(m0 + row) * ldA + k0 + sk);
            bv[p] = *reinterpret_cast<const int4*>(B + zB + (size_t)(n0 + row) * ldB + k0 + sk);
        }

        __syncthreads();
        #pragma unroll
        for (int p = 0; p < 4; ++p) {
            const int row = p * 32 + sr;
            *reinterpret_cast<int4*>(&As[row][sk]) = av[p];
            *reinterpret_cast<int4*>(&Bs[row][sk]) = bv[p];
        }
        __syncthreads();

        #pragma unroll
        for (int ks = 0; ks < 2; ++ks) {
            const int ko = ks * 32 + fq * 8;
            short8 ah[4];
            #pragma unroll
            for (int i = 0; i < 4; ++i)
                ah[i] = *reinterpret_cast<const short8*>(&As[wm + i*16 + fr][ko]);
            #pragma unroll
            for (int j = 0; j < 4; ++j) {
                short8 bh = *reinterpret_cast<const short8*>(&Bs[wn + j*16 + fr][ko]);
                #pragma unroll
                for (int i = 0; i < 4; ++i)
                    acc[i][j] = __builtin_amdgcn_mfma_f32_16x16x32_bf16(ah[i], bh, acc[i][j], 0, 0, 0);
            }
        }
    }

    #pragma unroll
    for (int i = 0; i < 4; ++i) {
        #pragma unroll
        for (int j = 0; j < 4; ++j) {
            const int col = n0 + wn + j*16 + fr;
            #pragma unroll
            for (int r = 0; r < 4; ++r) {
                const int row = m0 + wm + i*16 + fq*4 + r;
                C[zC + (size_t)row * ldC + col] = acc[i][j][r];
            }
        }
    }
}

// ---------------------------------------------------------------------------
// Column-softmax stats (softmax over the ROW index q, per column k).
// ---------------------------------------------------------------------------
__global__ __launch_bounds__(256)
void colstats_partial(const float* __restrict__ S, float* __restrict__ mP,
                      float* __restrict__ ZP, int rows_total, int cols, int rows_per)
{
    const int b = blockIdx.z;
    const int c = blockIdx.x * 256 + threadIdx.x;
    const int r0 = blockIdx.y * rows_per;
    const float* Sp = S + ((size_t)b * rows_total + r0) * cols + c;

    float m = -INFINITY, Z = 0.f;
    for (int q = 0; q < rows_per; ++q) {
        float s = Sp[(size_t)q * cols];
        float nm = fmaxf(m, s);
        Z = Z * __expf(m - nm) + __expf(s - nm);
        m = nm;
    }
    size_t o = ((size_t)b * gridDim.y + blockIdx.y) * cols + c;
    mP[o] = m;
    ZP[o] = Z;
}

__global__ __launch_bounds__(256)
void colstats_combine(const float* __restrict__ mP, const float* __restrict__ ZP,
                      float* __restrict__ mOut, float* __restrict__ rZ,
                      int cols, int chunks)
{
    const int b = blockIdx.y;
    const int c = blockIdx.x * 256 + threadIdx.x;
    float m = -INFINITY, Z = 0.f;
    for (int ch = 0; ch < chunks; ++ch) {
        size_t o = ((size_t)b * chunks + ch) * cols + c;
        float mi = mP[o];
        float Zi = ZP[o];
        float nm = fmaxf(m, mi);
        Z = Z * __expf(m - nm) + Zi * __expf(mi - nm);
        m = nm;
    }
    mOut[(size_t)b * cols + c] = m;
    rZ[(size_t)b * cols + c]   = 1.0f / Z;
}

// ---------------------------------------------------------------------------
// Normalize + split: P = exp(S - m_col) * rZ_col -> bf16 hi/lo pair.
// (Verbatim round 2; Plo is written but unused by gemm_pv — kept to hold
// everything upstream of PV bit-identical to the round-2 binary.)
// ---------------------------------------------------------------------------
__global__ __launch_bounds__(256)
void normalize_split(const float* __restrict__ S, const float* __restrict__ mIn,
                     const float* __restrict__ rZ, ushort_t* __restrict__ Phi,
                     ushort_t* __restrict__ Plo, size_t total4, int cols, int rowscols)
{
    size_t i4 = (size_t)blockIdx.x * 256 + threadIdx.x;
    if (i4 >= total4) return;
    size_t base = i4 * 4;
    int b   = (int)(base / (size_t)rowscols);
    int col = (int)(base % (size_t)cols);
    float4 s = *reinterpret_cast<const float4*>(S + base);
    const float* mv = mIn + (size_t)b * cols + col;
    const float* zv = rZ  + (size_t)b * cols + col;
    float p[4];
    p[0] = __expf(s.x - mv[0]) * zv[0];
    p[1] = __expf(s.y - mv[1]) * zv[1];
    p[2] = __expf(s.z - mv[2]) * zv[2];
    p[3] = __expf(s.w - mv[3]) * zv[3];
    unsigned h[4], l[4];
    #pragma unroll
    for (int j = 0; j < 4; ++j) {
        h[j] = f2bf(p[j]);
        l[j] = f2bf(p[j] - bf2f((ushort_t)h[j]));
    }
    uint2 hv, lv;
    hv.x = h[0] | (h[1] << 16); hv.y = h[2] | (h[3] << 16);
    lv.x = l[0] | (l[1] << 16); lv.y = l[2] | (l[3] << 16);
    *reinterpret_cast<uint2*>(Phi + base) = hv;
    *reinterpret_cast<uint2*>(Plo + base) = lv;
}

// ---------------------------------------------------------------------------
extern "C" void kernel_launch(void* const* d_in, const int* in_sizes, int n_in,
                              void* d_out, int out_size, void* d_ws, size_t ws_size,
                              hipStream_t stream)
{
    const float* x  = (const float*)d_in[0];
    const float* Wq = (const float*)d_in[1];
    const float* bq = (const float*)d_in[2];
    const float* Wk = (const float*)d_in[3];
    const float* bk = (const float*)d_in[4];
    const float* Wv = (const float*)d_in[5];
    const float* bv = (const float*)d_in[6];

    const int S = SEQ, E = EMB;
    const size_t MT = (size_t)BATCH * S;      // 8192
    const size_t MB = 1024 * 1024;

    // Workspace layout (verbatim round 2; overlays safe: lifetimes disjoint)
    char* base = (char*)d_ws;
    float*    Sc   = (float*)base;
    ushort_t* xhi  = (ushort_t*)base;
    ushort_t* xlo  = (ushort_t*)(base + 16 * MB);
    ushort_t* Wqth = (ushort_t*)(base + 32 * MB);
    ushort_t* Wqtl = (ushort_t*)(base + 34 * MB);
    ushort_t* Wkth = (ushort_t*)(base + 36 * MB);
    ushort_t* Wktl = (ushort_t*)(base + 38 * MB);
    ushort_t* Wvth = (ushort_t*)(base + 40 * MB);
    ushort_t* Wvtl = (ushort_t*)(base + 42 * MB);
    ushort_t* Qhi  = (ushort_t*)(base + 64 * MB);
    ushort_t* Qlo  = (ushort_t*)(base + 80 * MB);
    ushort_t* Khi  = (ushort_t*)(base + 96 * MB);
    ushort_t* Klo  = (ushort_t*)(base + 112 * MB);
    ushort_t* Phi  = (ushort_t*)(base + 64 * MB);   // overlays Q (dead)
    ushort_t* Plo  = (ushort_t*)(base + 96 * MB);   // overlays K (dead)
    ushort_t* Vth  = (ushort_t*)(base + 128 * MB);
    ushort_t* Vtl  = (ushort_t*)(base + 144 * MB);
    float* mC = (float*)(base + 160 * MB);
    float* rZ = mC + (size_t)BATCH * S;
    float* mP = rZ + (size_t)BATCH * S;
    float* ZP = mP + (size_t)BATCH * 8 * S;

    dim3 blk(256);

    // 1) Split x into bf16 hi/lo
    split_elem<<<8192, blk, 0, stream>>>(x, xhi, xlo, MT * E / 4);

    // 2) Split+transpose weights: Wt [n][e]
    dim3 gt(E / 32, E / 32);
    split_transpose<<<gt, blk, 0, stream>>>(Wq, Wqth, Wqtl, E, E);
    split_transpose<<<gt, blk, 0, stream>>>(Wk, Wkth, Wktl, E, E);
    split_transpose<<<gt, blk, 0, stream>>>(Wv, Wvth, Wvtl, E, E);

    // 3) Projections (NT): Q/K = x . Wt^T + b, split-stored
    dim3 gq(E / GBN, MT / GBM, 1);   // (8, 64)
    gemm_bf16pair<1, 1><<<gq, blk, 0, stream>>>(xhi, xlo, E, 0, Wqth, Wqtl, E, 0,
        nullptr, Qhi, Qlo, E, 0, E, 1.f, bq);
    gemm_bf16pair<1, 1><<<gq, blk, 0, stream>>>(xhi, xlo, E, 0, Wkth, Wktl, E, 0,
        nullptr, Khi, Klo, E, 0, E, 1.f, bk);
    // Vt[d][key] = Wvt . x^T + bv (per-row bias), split-stored, ldC = MT
    dim3 gv(MT / GBN, E / GBM, 1);   // (64, 8)
    gemm_bf16pair<2, 1><<<gv, blk, 0, stream>>>(Wvth, Wvtl, E, 0, xhi, xlo, E, 0,
        nullptr, Vth, Vtl, (int)MT, 0, E, 1.f, bv);

    // 4) Scores (NT, batched): Sc_b = Q_b . K_b^T / 32, fp32
    dim3 gs(S / GBN, S / GBM, BATCH);   // (16,16,4)
    gemm_bf16pair<0, 0><<<gs, blk, 0, stream>>>(Qhi, Qlo, E, (size_t)S * E,
        Khi, Klo, E, (size_t)S * E,
        Sc, nullptr, nullptr, S, (size_t)S * S, E, 0.03125f, nullptr);

    // 5) Column softmax stats
    dim3 g3(S / 256, 8, BATCH);
    colstats_partial<<<g3, blk, 0, stream>>>(Sc, mP, ZP, S, S, S / 8);
    dim3 g4(S / 256, BATCH);
    colstats_combine<<<g4, blk, 0, stream>>>(mP, ZP, mC, rZ, S, 8);

    // 6) Normalize + split P
    size_t total4 = (size_t)BATCH * S * S / 4;
    normalize_split<<<(unsigned)((total4 + 255) / 256), blk, 0, stream>>>(
        Sc, mC, rZ, Phi, Plo, total4, S, S * S);

    // 7) Output (NT, 1-term bf16, batched): out_b = P_b . Vt^T
    dim3 go(E / 128, S / 128, BATCH);   // (8,16,4)
    gemm_pv<<<go, blk, 0, stream>>>(Phi, S, (size_t)S * S,
        Vth, (int)MT, (size_t)S,
        (float*)d_out, E, (size_t)S * E, S);
}

// Round 7
// 633.255 us; speedup vs baseline: 1.8533x; 1.0249x over previous
//
#include <hip/hip_runtime.h>
#include <math.h>

typedef unsigned short ushort_t;
typedef __attribute__((ext_vector_type(8))) short short8;
typedef __attribute__((ext_vector_type(4))) float floatx4;

#define BATCH 4
#define SEQ   2048
#define EMB   1024

// MFMA GEMM tile
#define GBM 128
#define GBN 128
#define GBK 32
#define LDSK 40   // padded LDS k-stride in bf16 elems (80 B rows -> 2-way bank alias, free)

// ---------------------------------------------------------------------------
// XCD-aware block decode. 1-D grid; bid%8 is assumed XCD id (round-robin
// dispatch). Each XCD owns a contiguous range of "groups" along the larger
// tile axis and iterates all tiles of the smaller axis, so its L2 working
// set is ~(groups_per_xcd * big-axis tile) + (whole small axis).
// GROUP_M=1: groups over (bz,by), fast axis bx. Requires ny*nb % 8 == 0.
// GROUP_M=0: groups over (bz,bx), fast axis by. Requires nx*nb % 8 == 0.
// ---------------------------------------------------------------------------
template<int GROUP_M>
__device__ __forceinline__ void xcd_decode(int nx, int ny, int nb,
                                           int& bx, int& by, int& bz)
{
    const int bid = blockIdx.x;
    const int xcd = bid & 7;
    const int s   = bid >> 3;
    if (GROUP_M) {
        const int gi = s / nx;
        bx = s - gi * nx;
        const int g = xcd * ((ny * nb) >> 3) + gi;
        by = g % ny;
        bz = g / ny;
    } else {
        const int gi = s / ny;
        by = s - gi * ny;
        const int g = xcd * ((nx * nb) >> 3) + gi;
        bx = g % nx;
        bz = g / nx;
    }
}

// ---------------------------------------------------------------------------
// bf16 split helpers (RNE)
// ---------------------------------------------------------------------------
__device__ __forceinline__ ushort_t f2bf(float f) {
    unsigned u = __float_as_uint(f);
    u += 0x7fff + ((u >> 16) & 1);
    return (ushort_t)(u >> 16);
}
__device__ __forceinline__ float bf2f(ushort_t h) {
    return __uint_as_float(((unsigned)h) << 16);
}

// ---------------------------------------------------------------------------
// Elementwise split: fp32 -> (hi, lo) bf16 arrays. n4 = count/4.
// ---------------------------------------------------------------------------
__global__ __launch_bounds__(256)
void split_elem(const float* __restrict__ in, ushort_t* __restrict__ hi,
                ushort_t* __restrict__ lo, size_t n4)
{
    size_t i = (size_t)blockIdx.x * 256 + threadIdx.x;
    if (i >= n4) return;
    float4 v = reinterpret_cast<const float4*>(in)[i];
    float vv[4] = {v.x, v.y, v.z, v.w};
    unsigned h[4], l[4];
    #pragma unroll
    for (int j = 0; j < 4; ++j) {
        h[j] = f2bf(vv[j]);
        l[j] = f2bf(vv[j] - bf2f((ushort_t)h[j]));
    }
    uint2 hv, lv;
    hv.x = h[0] | (h[1] << 16); hv.y = h[2] | (h[3] << 16);
    lv.x = l[0] | (l[1] << 16); lv.y = l[2] | (l[3] << 16);
    *reinterpret_cast<uint2*>(hi + i * 4) = hv;
    *reinterpret_cast<uint2*>(lo + i * 4) = lv;
}

// ---------------------------------------------------------------------------
// Split + transpose: W [rows][cols] fp32 -> T [cols][rows] bf16 hi/lo.
// ---------------------------------------------------------------------------
__global__ __launch_bounds__(256)
void split_transpose(const float* __restrict__ W, ushort_t* __restrict__ Thi,
                     ushort_t* __restrict__ Tlo, int rows, int cols)
{
    __shared__ float tile[32][33];
    const int r0 = blockIdx.y * 32, c0 = blockIdx.x * 32;
    const int tr = threadIdx.x >> 5;   // 0..7
    const int tc = threadIdx.x & 31;
    #pragma unroll
    for (int rr = 0; rr < 32; rr += 8)
        tile[tr + rr][tc] = W[(size_t)(r0 + tr + rr) * cols + c0 + tc];
    __syncthreads();
    #pragma unroll
    for (int rr = 0; rr < 32; rr += 8) {
        float v = tile[tc][tr + rr];
        size_t o = (size_t)(c0 + tr + rr) * rows + r0 + tc;
        ushort_t h = f2bf(v);
        Thi[o] = h;
        Tlo[o] = f2bf(v - bf2f(h));
    }
}

// ---------------------------------------------------------------------------
// NT MFMA GEMM on split-bf16 pairs (round-2 core + XCD swizzle):
//   C[m][n] = alpha * sum_k A[m][k]*B[n][k]  (+ bias)
// A = Ahi+Alo, B = Bhi+Blo (fp32 emulation: hh + hl + lh).
// BIAS_MODE: 0 none, 1 per-n (bias[col]), 2 per-m (bias[row])
// STORE_MODE: 0 -> fp32 to C; 1 -> split bf16 to Chi/Clo; 2 -> bf16 to Chi
// ---------------------------------------------------------------------------
template<int BIAS_MODE, int STORE_MODE, int GROUP_M>
__global__ __launch_bounds__(256)
void gemm_bf16pair(const ushort_t* __restrict__ Ahi, const ushort_t* __restrict__ Alo,
                   int ldA, size_t bsA,
                   const ushort_t* __restrict__ Bhi, const ushort_t* __restrict__ Blo,
                   int ldB, size_t bsB,
                   float* __restrict__ C, ushort_t* __restrict__ Chi, ushort_t* __restrict__ Clo,
                   int ldC, size_t bsC,
                   int K, float alpha, const float* __restrict__ bias,
                   int nx, int ny, int nb)
{
    int bx, by, bz;
    xcd_decode<GROUP_M>(nx, ny, nb, bx, by, bz);

    const size_t zA = (size_t)bz * bsA;
    const size_t zB = (size_t)bz * bsB;
    const size_t zC = (size_t)bz * bsC;

    __shared__ alignas(16) ushort_t As[2][GBM][LDSK];   // [hi/lo][m][k]
    __shared__ alignas(16) ushort_t Bs[2][GBN][LDSK];   // [hi/lo][n][k]

    const int t  = threadIdx.x;
    const int m0 = by * GBM;
    const int n0 = bx * GBN;

    const int sr = t >> 2;          // 0..63
    const int sk = (t & 3) * 8;

    const int lane = t & 63;
    const int wid  = t >> 6;        // wave 0..3
    const int wm = (wid & 1) * 64;
    const int wn = (wid >> 1) * 64;
    const int fr = lane & 15;       // fragment row (m or n)
    const int fq = lane >> 4;       // k-quad: k = fq*8 + j

    floatx4 acc[4][4];
    #pragma unroll
    for (int i = 0; i < 4; ++i)
        #pragma unroll
        for (int j = 0; j < 4; ++j)
            #pragma unroll
            for (int r = 0; r < 4; ++r) acc[i][j][r] = 0.f;

    for (int k0 = 0; k0 < K; k0 += GBK) {
        const size_t aoff = zA + (size_t)(m0 + sr) * ldA + k0 + sk;
        const size_t boff = zB + (size_t)(n0 + sr) * ldB + k0 + sk;
        const size_t astep = (size_t)64 * ldA;
        const size_t bstep = (size_t)64 * ldB;
        int4 a0 = *reinterpret_cast<const int4*>(Ahi + aoff);
        int4 a1 = *reinterpret_cast<const int4*>(Ahi + aoff + astep);
        int4 a2 = *reinterpret_cast<const int4*>(Alo + aoff);
        int4 a3 = *reinterpret_cast<const int4*>(Alo + aoff + astep);
        int4 b0 = *reinterpret_cast<const int4*>(Bhi + boff);
        int4 b1 = *reinterpret_cast<const int4*>(Bhi + boff + bstep);
        int4 b2 = *reinterpret_cast<const int4*>(Blo + boff);
        int4 b3 = *reinterpret_cast<const int4*>(Blo + boff + bstep);

        __syncthreads();   // prior iter's LDS reads complete
        *reinterpret_cast<int4*>(&As[0][sr     ][sk]) = a0;
        *reinterpret_cast<int4*>(&As[0][sr + 64][sk]) = a1;
        *reinterpret_cast<int4*>(&As[1][sr     ][sk]) = a2;
        *reinterpret_cast<int4*>(&As[1][sr + 64][sk]) = a3;
        *reinterpret_cast<int4*>(&Bs[0][sr     ][sk]) = b0;
        *reinterpret_cast<int4*>(&Bs[0][sr + 64][sk]) = b1;
        *reinterpret_cast<int4*>(&Bs[1][sr     ][sk]) = b2;
        *reinterpret_cast<int4*>(&Bs[1][sr + 64][sk]) = b3;
        __syncthreads();

        short8 ah[4], al[4];
        #pragma unroll
        for (int i = 0; i < 4; ++i) {
            ah[i] = *reinterpret_cast<const short8*>(&As[0][wm + i*16 + fr][fq*8]);
            al[i] = *reinterpret_cast<const short8*>(&As[1][wm + i*16 + fr][fq*8]);
        }
        #pragma unroll
        for (int j = 0; j < 4; ++j) {
            short8 bh = *reinterpret_cast<const short8*>(&Bs[0][wn + j*16 + fr][fq*8]);
            short8 bl = *reinterpret_cast<const short8*>(&Bs[1][wn + j*16 + fr][fq*8]);
            #pragma unroll
            for (int i = 0; i < 4; ++i) {
                acc[i][j] = __builtin_amdgcn_mfma_f32_16x16x32_bf16(ah[i], bh, acc[i][j], 0, 0, 0);
                acc[i][j] = __builtin_amdgcn_mfma_f32_16x16x32_bf16(ah[i], bl, acc[i][j], 0, 0, 0);
                acc[i][j] = __builtin_amdgcn_mfma_f32_16x16x32_bf16(al[i], bh, acc[i][j], 0, 0, 0);
            }
        }
    }

    // Epilogue. C/D layout: col = lane&15, row = (lane>>4)*4 + r  [m89-verified]
    #pragma unroll
    for (int i = 0; i < 4; ++i) {
        #pragma unroll
        for (int j = 0; j < 4; ++j) {
            const int col = n0 + wn + j*16 + fr;
            float bn = 0.f;
            if (BIAS_MODE == 1) bn = bias[col];
            #pragma unroll
            for (int r = 0; r < 4; ++r) {
                const int row = m0 + wm + i*16 + fq*4 + r;
                float v = acc[i][j][r] * alpha + bn;
                if (BIAS_MODE == 2) v += bias[row];
                const size_t o = zC + (size_t)row * ldC + col;
                if constexpr (STORE_MODE == 1) {
                    ushort_t h = f2bf(v);
                    Chi[o] = h;
                    Clo[o] = f2bf(v - bf2f(h));
                } else if constexpr (STORE_MODE == 2) {
                    Chi[o] = f2bf(v);
                } else {
                    C[o] = v;
                }
            }
        }
    }
}

// ---------------------------------------------------------------------------
// Plain 1-term bf16 NT GEMM for P @ V^T (round-6 core + XCD swizzle).
// BKT=64, LDS row stride 72 (144 B: 2-way bank alias, free).
// ---------------------------------------------------------------------------
template<int GROUP_M>
__global__ __launch_bounds__(256)
void gemm_pv(const ushort_t* __restrict__ A, int ldA, size_t bsA,
             const ushort_t* __restrict__ B, int ldB, size_t bsB,
             float* __restrict__ C, int ldC, size_t bsC, int K,
             int nx, int ny, int nb)
{
    int bx, by, bz;
    xcd_decode<GROUP_M>(nx, ny, nb, bx, by, bz);

    const size_t zA = (size_t)bz * bsA;
    const size_t zB = (size_t)bz * bsB;
    const size_t zC = (size_t)bz * bsC;

    __shared__ alignas(16) ushort_t As[128][72];
    __shared__ alignas(16) ushort_t Bs[128][72];

    const int t  = threadIdx.x;
    const int m0 = by * 128;
    const int n0 = bx * 128;

    const int sr = t >> 3;          // 0..31
    const int sk = (t & 7) * 8;     // 0..56

    const int lane = t & 63;
    const int wid  = t >> 6;
    const int wm = (wid & 1) * 64;
    const int wn = (wid >> 1) * 64;
    const int fr = lane & 15;
    const int fq = lane >> 4;

    floatx4 acc[4][4];
    #pragma unroll
    for (int i = 0; i < 4; ++i)
        #pragma unroll
        for (int j = 0; j < 4; ++j)
            #pragma unroll
            for (int r = 0; r < 4; ++r) acc[i][j][r] = 0.f;

    for (int k0 = 0; k0 < K; k0 += 64) {
        int4 av[4], bv[4];
        #pragma unroll
        for (int p = 0; p < 4; ++p) {
            const int row = p * 32 + sr;
            av[p] = *reinterpret_cast<const int4*>(A + zA + (size_t)(m0 + row) * ldA + k0 + sk);
            bv[p] = *reinterpret_cast<const int4*>(B + zB + (size_t)(n0 + row) * ldB + k0 + sk);
        }

        __syncthreads();
        #pragma unroll
        for (int p = 0; p < 4; ++p) {
            const int row = p * 32 + sr;
            *reinterpret_cast<int4*>(&As[row][sk]) = av[p];
            *reinterpret_cast<int4*>(&Bs[row][sk]) = bv[p];
        }
        __syncthreads();

        #pragma unroll
        for (int ks = 0; ks < 2; ++ks) {
            const int ko = ks * 32 + fq * 8;
            short8 ah[4];
            #pragma unroll
            for (int i = 0; i < 4; ++i)
                ah[i] = *reinterpret_cast<const short8*>(&As[wm + i*16 + fr][ko]);
            #pragma unroll
            for (int j = 0; j < 4; ++j) {
                short8 bh = *reinterpret_cast<const short8*>(&Bs[wn + j*16 + fr][ko]);
                #pragma unroll
                for (int i = 0; i < 4; ++i)
                    acc[i][j] = __builtin_amdgcn_mfma_f32_16x16x32_bf16(ah[i], bh, acc[i][j], 0, 0, 0);
            }
        }
    }

    #pragma unroll
    for (int i = 0; i < 4; ++i) {
        #pragma unroll
        for (int j = 0; j < 4; ++j) {
            const int col = n0 + wn + j*16 + fr;
            #pragma unroll
            for (int r = 0; r < 4; ++r) {
                const int row = m0 + wm + i*16 + fq*4 + r;
                C[zC + (size_t)row * ldC + col] = acc[i][j][r];
            }
        }
    }
}

// ---------------------------------------------------------------------------
// Column-softmax stats (softmax over the ROW index q, per column k).
// ---------------------------------------------------------------------------
__global__ __launch_bounds__(256)
void colstats_partial(const float* __restrict__ S, float* __restrict__ mP,
                      float* __restrict__ ZP, int rows_total, int cols, int rows_per)
{
    const int b = blockIdx.z;
    const int c = blockIdx.x * 256 + threadIdx.x;
    const int r0 = blockIdx.y * rows_per;
    const float* Sp = S + ((size_t)b * rows_total + r0) * cols + c;

    float m = -INFINITY, Z = 0.f;
    for (int q = 0; q < rows_per; ++q) {
        float s = Sp[(size_t)q * cols];
        float nm = fmaxf(m, s);
        Z = Z * __expf(m - nm) + __expf(s - nm);
        m = nm;
    }
    size_t o = ((size_t)b * gridDim.y + blockIdx.y) * cols + c;
    mP[o] = m;
    ZP[o] = Z;
}

__global__ __launch_bounds__(256)
void colstats_combine(const float* __restrict__ mP, const float* __restrict__ ZP,
                      float* __restrict__ mOut, float* __restrict__ rZ,
                      int cols, int chunks)
{
    const int b = blockIdx.y;
    const int c = blockIdx.x * 256 + threadIdx.x;
    float m = -INFINITY, Z = 0.f;
    for (int ch = 0; ch < chunks; ++ch) {
        size_t o = ((size_t)b * chunks + ch) * cols + c;
        float mi = mP[o];
        float Zi = ZP[o];
        float nm = fmaxf(m, mi);
        Z = Z * __expf(m - nm) + Zi * __expf(mi - nm);
        m = nm;
    }
    mOut[(size_t)b * cols + c] = m;
    rZ[(size_t)b * cols + c]   = 1.0f / Z;
}

// ---------------------------------------------------------------------------
// Normalize: P = exp(S - m_col) * rZ_col -> plain bf16 (hi only).
// ---------------------------------------------------------------------------
__global__ __launch_bounds__(256)
void normalize_bf16(const float* __restrict__ S, const float* __restrict__ mIn,
                    const float* __restrict__ rZ, ushort_t* __restrict__ Phi,
                    size_t total4, int cols, int rowscols)
{
    size_t i4 = (size_t)blockIdx.x * 256 + threadIdx.x;
    if (i4 >= total4) return;
    size_t base = i4 * 4;
    int b   = (int)(base / (size_t)rowscols);
    int col = (int)(base % (size_t)cols);
    float4 s = *reinterpret_cast<const float4*>(S + base);
    const float* mv = mIn + (size_t)b * cols + col;
    const float* zv = rZ  + (size_t)b * cols + col;
    unsigned h0 = f2bf(__expf(s.x - mv[0]) * zv[0]);
    unsigned h1 = f2bf(__expf(s.y - mv[1]) * zv[1]);
    unsigned h2 = f2bf(__expf(s.z - mv[2]) * zv[2]);
    unsigned h3 = f2bf(__expf(s.w - mv[3]) * zv[3]);
    uint2 hv;
    hv.x = h0 | (h1 << 16);
    hv.y = h2 | (h3 << 16);
    *reinterpret_cast<uint2*>(Phi + base) = hv;
}

// ---------------------------------------------------------------------------
extern "C" void kernel_launch(void* const* d_in, const int* in_sizes, int n_in,
                              void* d_out, int out_size, void* d_ws, size_t ws_size,
                              hipStream_t stream)
{
    const float* x  = (const float*)d_in[0];
    const float* Wq = (const float*)d_in[1];
    const float* bq = (const float*)d_in[2];
    const float* Wk = (const float*)d_in[3];
    const float* bk = (const float*)d_in[4];
    const float* Wv = (const float*)d_in[5];
    const float* bv = (const float*)d_in[6];

    const int S = SEQ, E = EMB;
    const size_t MT = (size_t)BATCH * S;      // 8192
    const size_t MB = 1024 * 1024;

    // Workspace layout (stream-ordered overlays; lifetimes disjoint)
    char* base = (char*)d_ws;
    float*    Sc   = (float*)base;
    ushort_t* xhi  = (ushort_t*)base;
    ushort_t* xlo  = (ushort_t*)(base + 16 * MB);
    ushort_t* Wqth = (ushort_t*)(base + 32 * MB);
    ushort_t* Wqtl = (ushort_t*)(base + 34 * MB);
    ushort_t* Wkth = (ushort_t*)(base + 36 * MB);
    ushort_t* Wktl = (ushort_t*)(base + 38 * MB);
    ushort_t* Wvth = (ushort_t*)(base + 40 * MB);
    ushort_t* Wvtl = (ushort_t*)(base + 42 * MB);
    ushort_t* Qhi  = (ushort_t*)(base + 64 * MB);
    ushort_t* Qlo  = (ushort_t*)(base + 80 * MB);
    ushort_t* Khi  = (ushort_t*)(base + 96 * MB);
    ushort_t* Klo  = (ushort_t*)(base + 112 * MB);
    ushort_t* Phi  = (ushort_t*)(base + 64 * MB);   // overlays Q (dead)
    ushort_t* Vth  = (ushort_t*)(base + 128 * MB);
    float* mC = (float*)(base + 160 * MB);
    float* rZ = mC + (size_t)BATCH * S;
    float* mP = rZ + (size_t)BATCH * S;
    float* ZP = mP + (size_t)BATCH * 8 * S;

    dim3 blk(256);

    // 1) Split x into bf16 hi/lo
    split_elem<<<8192, blk, 0, stream>>>(x, xhi, xlo, MT * E / 4);

    // 2) Split+transpose weights: Wt [n][e]
    dim3 gt(E / 32, E / 32);
    split_transpose<<<gt, blk, 0, stream>>>(Wq, Wqth, Wqtl, E, E);
    split_transpose<<<gt, blk, 0, stream>>>(Wk, Wkth, Wktl, E, E);
    split_transpose<<<gt, blk, 0, stream>>>(Wv, Wvth, Wvtl, E, E);

    // 3) Projections (NT): Q/K = x . Wt^T + b, split-stored.
    //    nx=8 (E/128), ny=64 (MT/128): group by m (x-tiles per XCD, all W hot).
    gemm_bf16pair<1, 1, 1><<<512, blk, 0, stream>>>(xhi, xlo, E, 0, Wqth, Wqtl, E, 0,
        nullptr, Qhi, Qlo, E, 0, E, 1.f, bq, 8, 64, 1);
    gemm_bf16pair<1, 1, 1><<<512, blk, 0, stream>>>(xhi, xlo, E, 0, Wkth, Wktl, E, 0,
        nullptr, Khi, Klo, E, 0, E, 1.f, bk, 8, 64, 1);
    // Vt[d][key] = Wvt . x^T + bv (per-row bias), bf16-only store, ldC = MT.
    //    nx=64 (x-tiles), ny=8 (Wv-tiles): group by n.
    gemm_bf16pair<2, 2, 0><<<512, blk, 0, stream>>>(Wvth, Wvtl, E, 0, xhi, xlo, E, 0,
        nullptr, Vth, nullptr, (int)MT, 0, E, 1.f, bv, 64, 8, 1);

    // 4) Scores (NT, batched): Sc_b = Q_b . K_b^T / 32, fp32.
    //    nx=16, ny=16, nb=4: group by (b,m).
    gemm_bf16pair<0, 0, 1><<<1024, blk, 0, stream>>>(Qhi, Qlo, E, (size_t)S * E,
        Khi, Klo, E, (size_t)S * E,
        Sc, nullptr, nullptr, S, (size_t)S * S, E, 0.03125f, nullptr, 16, 16, 4);

    // 5) Column softmax stats
    dim3 g3(S / 256, 8, BATCH);
    colstats_partial<<<g3, blk, 0, stream>>>(Sc, mP, ZP, S, S, S / 8);
    dim3 g4(S / 256, BATCH);
    colstats_combine<<<g4, blk, 0, stream>>>(mP, ZP, mC, rZ, S, 8);

    // 6) Normalize -> plain bf16 P (no lo plane)
    size_t total4 = (size_t)BATCH * S * S / 4;
    normalize_bf16<<<(unsigned)((total4 + 255) / 256), blk, 0, stream>>>(
        Sc, mC, rZ, Phi, total4, S, S * S);

    // 7) Output (NT, 1-term bf16, batched): out_b = P_b . Vt^T.
    //    nx=8, ny=16, nb=4: group by (b,m).
    gemm_pv<1><<<512, blk, 0, stream>>>(Phi, S, (size_t)S * S,
        Vth, (int)MT, (size_t)S,
        (float*)d_out, E, (size_t)S * E, S, 8, 16, 4);
}